// Round 15
// baseline (145.370 us; speedup 1.0000x reference)
//
#include <hip/hip_runtime.h>

#define ALG_DIM 248
#define ROWS 32                    // rows per main-kernel block
#define KSPLIT 4
#define KPB 62                     // k-slots per block (248/4)
#define PMAX 1024                  // safety clamp for padded bucket length
#define CB 32                      // prep chunk blocks
#define PLSTRIDE_B 3984            // plane stride bytes (248*16 + 16; /4 = 996 ≡ 4 mod 32)
#define PLSTRIDE_DW 996

typedef __fp16 h2v __attribute__((ext_vector_type(2)));
union H2U { unsigned u; h2v h; };

// ---------- prep: ONE wide kernel, every block redundantly sorts ----------
// 32 blocks x 256 threads. Each block scans ALL of idx_k once (120 KB,
// L2-broadcast), building htot (global histogram) and hpre (histogram of
// elements before its own chunk) in the same pass. All blocks then compute
// identical ranks (deterministic), so each block's scatter cursors are just
// rank*stride + hpre[k] — no inter-block communication at all. Block 0 also
// writes meta/perm/ssz and the zero-pad tails [size, trip+8) (disjoint from
// the real-entry regions other blocks fill -> race-free).
// Lessons encoded: r13 grid.sync ~100us, r14 single-block fusion -9us —
// kernel boundaries are cheap (~3-5us) but narrow kernels are not; this
// keeps everything 32-blocks-wide while cutting 4 dispatches to 2.
// packed.x: lo16 = i*16, hi16 = j*16 (within-plane byte offsets);
// packed.y: coeff duplicated as f16x2.

__global__ __launch_bounds__(256) void k_prep2(
    const int* __restrict__ idx_i, const int* __restrict__ idx_j,
    const int* __restrict__ idx_k, const float* __restrict__ coeff,
    int* __restrict__ meta, int* __restrict__ perm, int* __restrict__ ssz,
    uint2* __restrict__ packedP, int nnz)
{
    __shared__ int htot[256];     // global bucket sizes
    __shared__ int hpre[256];     // bucket sizes over [0, my chunk start)
    __shared__ int red[256];
    __shared__ int ssl[256];      // size by slot (block 0 only, for pads)
    __shared__ int cur[256];      // my chunk's write cursors
    __shared__ int lim[256];      // overflow limits

    const int b = blockIdx.x, tid = threadIdx.x;
    const int chunk = (nnz + CB - 1) / CB;
    const int lo = b * chunk, hi = min(nnz, lo + chunk);

    htot[tid] = 0;
    hpre[tid] = 0;
    __syncthreads();

    for (int t = tid; t < nnz; t += 256) {
        const int k = idx_k[t];
        atomicAdd(&htot[k], 1);
        if (t < lo) atomicAdd(&hpre[k], 1);
    }
    __syncthreads();

    red[tid] = (tid < ALG_DIM) ? htot[tid] : 0;
    __syncthreads();
    for (int off = 128; off > 0; off >>= 1) {
        if (tid < off) red[tid] = max(red[tid], red[tid + off]);
        __syncthreads();
    }
    int P = (red[0] + 7) & ~7;
    P = max(P, 8);
    P = min(P, PMAX);
    const int stride = P + 8;              // per-slot element stride

    int rank = 0, mysz = 0;
    if (tid < ALG_DIM) {
        mysz = htot[tid];
        for (int k = 0; k < ALG_DIM; ++k) {
            const int s2 = htot[k];
            rank += (s2 > mysz) || (s2 == mysz && k < tid);   // unique ranks
        }
        const int base = rank * stride;
        cur[tid] = base + hpre[tid];       // my chunk starts after earlier chunks
        lim[tid] = base + P;               // overflow guard (only if P clamped)
    }

    if (b == 0) {                          // block-uniform branch: syncs legal
        if (tid == 0) meta[0] = P;
        if (tid < ALG_DIM) {
            perm[rank] = tid;
            ssz[rank]  = mysz;
            ssl[rank]  = mysz;
        }
        __syncthreads();
        if (tid < ALG_DIM) {
            // pad my slot: trip = round8(size of my 16-group's leader slot)
            const int by = rank / KPB;
            const int L  = by * KPB + (((rank - by * KPB) >> 4) << 4);
            const int trip = (ssl[L] + 7) & ~7;
            const int base = rank * stride;
            for (int e = mysz; e < trip + 8; ++e)
                packedP[base + e] = make_uint2(0u, 0u);
        }
    }
    __syncthreads();

    for (int t = lo + tid; t < hi; t += 256) {
        const int k = idx_k[t];
        const int pos = atomicAdd(&cur[k], 1);      // LDS atomic only
        if (pos < lim[k]) {
            const float c = coeff[t];
            H2U hc; hc.h = __builtin_amdgcn_cvt_pkrtz(c, c);
            uint2 p;
            p.x = ((unsigned)idx_i[t] << 4) | ((unsigned)idx_j[t] << 20);
            p.y = hc.u;
            packedP[pos] = p;
        }
    }
}

// ---------- main: plane-layout f16 gather (unchanged since round 10) ----------
// 256 threads = 64 streams x 4 lanes over 32 rows x 62 slots. x,y as f16 in
// 4 LDS planes: (col i, rows 8s..8s+7) at byte s*3984 + i*16. Lane q folds
// q*3984 into its base once; gather = ds_read_b128 at base + i*16, bank
// window (i*4 + 4q) mod 32 sweeps all 32 banks as i varies. 12 VALU + 2 b128
// per triple; f16 accumulators flushed to fp32 every 32 triples.

__global__ __launch_bounds__(256, 4) void k_main(
    const float* __restrict__ x, const float* __restrict__ y,
    const uint4* __restrict__ packed4,
    const int* __restrict__ meta, const int* __restrict__ perm,
    const int* __restrict__ ssz,
    const float* __restrict__ alpha_p, float* __restrict__ out)
{
    __shared__ __align__(16) unsigned xs32[4 * PLSTRIDE_DW];
    __shared__ __align__(16) unsigned ys32[4 * PLSTRIDE_DW];

    const int tid = threadIdx.x;
    const int r0  = blockIdx.x * ROWS;

    for (int u = tid; u < (ALG_DIM / 4) * (ROWS / 2); u += 256) {
        const int rp = u & 15;
        const int cq = u >> 4;
        const size_t ra = (size_t)(r0 + 2 * rp) * ALG_DIM + 4 * cq;
        const float4 xa = *reinterpret_cast<const float4*>(x + ra);
        const float4 xb = *reinterpret_cast<const float4*>(x + ra + ALG_DIM);
        const float4 ya = *reinterpret_cast<const float4*>(y + ra);
        const float4 yb = *reinterpret_cast<const float4*>(y + ra + ALG_DIM);
        const int pbase = (rp >> 2) * PLSTRIDE_DW + (rp & 3);
#define STG(d, XA, XB, YA, YB)                                                  \
        {                                                                       \
            const int dw = pbase + (4 * cq + (d)) * 4;                          \
            H2U hx; hx.h = __builtin_amdgcn_cvt_pkrtz(XA, XB);                  \
            H2U hy; hy.h = __builtin_amdgcn_cvt_pkrtz(YA, YB);                  \
            xs32[dw] = hx.u;                                                    \
            ys32[dw] = hy.u;                                                    \
        }
        STG(0, xa.x, xb.x, ya.x, yb.x)
        STG(1, xa.y, xb.y, ya.y, yb.y)
        STG(2, xa.z, xb.z, ya.z, yb.z)
        STG(3, xa.w, xb.w, ya.w, yb.w)
#undef STG
    }
    __syncthreads();

    const int   P     = meta[0];
    const float alpha = alpha_p[0];
    const int   S     = tid >> 2;            // stream 0..63 (owns one slot)
    const int   q     = tid & 3;             // my plane (rows 8q..8q+7)

    const char* xsb = reinterpret_cast<const char*>(xs32) + q * PLSTRIDE_B;
    const char* ysb = reinterpret_cast<const char*>(ys32) + q * PLSTRIDE_B;

    if (S < KPB) {
        const int p = blockIdx.y * KPB + S;
        const int k = perm[p];

        const int pw   = blockIdx.y * KPB + ((tid >> 6) << 4);
        const int trip = __builtin_amdgcn_readfirstlane((ssz[pw] + 7) & ~7);
        const int nH   = trip >> 1;          // uint4s (2 triples each)

        const uint4* tp = packed4 + (size_t)p * ((size_t)(P + 8) >> 1);

        float a0 = 0.f, a1 = 0.f, a2 = 0.f, a3 = 0.f,
              a4 = 0.f, a5 = 0.f, a6 = 0.f, a7 = 0.f;

        uint4 cur = tp[0];

#define PROC(PW, PC)                                                            \
        {                                                                       \
            const unsigned ox = (PW) & 0xFFFFu;                                 \
            const unsigned oy = (PW) >> 16;                                     \
            const uint4 wx = *reinterpret_cast<const uint4*>(xsb + ox);         \
            const uint4 wy = *reinterpret_cast<const uint4*>(ysb + oy);         \
            H2U cc; cc.u = (PC);                                                \
            H2U ux, uy;                                                         \
            ux.u = wx.x; uy.u = wy.x; c0 = (ux.h * uy.h) * cc.h + c0;           \
            ux.u = wx.y; uy.u = wy.y; c1 = (ux.h * uy.h) * cc.h + c1;           \
            ux.u = wx.z; uy.u = wy.z; c2 = (ux.h * uy.h) * cc.h + c2;           \
            ux.u = wx.w; uy.u = wy.w; c3 = (ux.h * uy.h) * cc.h + c3;           \
        }

        for (int ch = 0; ch < nH; ch += 16) {            // 32-triple window
            h2v c0 = (h2v)0.0f, c1 = (h2v)0.0f, c2 = (h2v)0.0f, c3 = (h2v)0.0f;
            const int hend = min(ch + 16, nH);
#pragma unroll 2
            for (int hh = ch; hh < hend; ++hh) {
                const uint4 nxt = tp[hh + 1];  // prefetch (pads cover over-read)
                PROC(cur.x, cur.y)
                PROC(cur.z, cur.w)
                cur = nxt;
            }
            a0 += (float)c0.x; a1 += (float)c0.y;
            a2 += (float)c1.x; a3 += (float)c1.y;
            a4 += (float)c2.x; a5 += (float)c2.y;
            a6 += (float)c3.x; a7 += (float)c3.y;
        }
#undef PROC

        const int rbase = r0 + (q << 3);
        out[(size_t)(rbase + 0) * ALG_DIM + k] = alpha * a0;
        out[(size_t)(rbase + 1) * ALG_DIM + k] = alpha * a1;
        out[(size_t)(rbase + 2) * ALG_DIM + k] = alpha * a2;
        out[(size_t)(rbase + 3) * ALG_DIM + k] = alpha * a3;
        out[(size_t)(rbase + 4) * ALG_DIM + k] = alpha * a4;
        out[(size_t)(rbase + 5) * ALG_DIM + k] = alpha * a5;
        out[(size_t)(rbase + 6) * ALG_DIM + k] = alpha * a6;
        out[(size_t)(rbase + 7) * ALG_DIM + k] = alpha * a7;
    }
}

// ---------- launch ----------

extern "C" void kernel_launch(void* const* d_in, const int* in_sizes, int n_in,
                              void* d_out, int out_size, void* d_ws, size_t ws_size,
                              hipStream_t stream) {
    const float* x      = (const float*)d_in[0];
    const float* y      = (const float*)d_in[1];
    const int*   idx_i  = (const int*)d_in[2];
    const int*   idx_j  = (const int*)d_in[3];
    const int*   idx_k  = (const int*)d_in[4];
    const float* coeff  = (const float*)d_in[5];
    const float* alpha  = (const float*)d_in[6];
    float*       out    = (float*)d_out;

    const int nnz   = in_sizes[2];
    const int batch = in_sizes[0] / ALG_DIM;

    // ws: [meta @0][perm @1K][ssz @2K][packedP @4K]
    char*  ws      = (char*)d_ws;
    int*   meta    = (int*)ws;
    int*   perm    = (int*)(ws + 1024);
    int*   ssz     = (int*)(ws + 2048);
    uint2* packedP = (uint2*)(ws + 4096);

    k_prep2<<<CB, 256, 0, stream>>>(idx_i, idx_j, idx_k, coeff,
                                    meta, perm, ssz, packedP, nnz);

    dim3 grid(batch / ROWS, KSPLIT);
    k_main<<<grid, 256, 0, stream>>>(x, y, (const uint4*)packedP, meta, perm, ssz,
                                     alpha, out);
}